// Round 3
// baseline (401.561 us; speedup 1.0000x reference)
//
#include <hip/hip_runtime.h>

// x = (32, 256, 56, 56) fp32; 16 groups of 16 channels
#define M_BATCH 32
#define D_FEAT 256
#define HW 3136
#define NGROUPS 16
#define GS 16
#define NTOT (M_BATCH * HW)
#define TRI 136
#define EPS_W 1e-6f
#define P4 (HW / 4)  // 784 float4 column-groups per channel row

__device__ __host__ constexpr int tidx(int i, int j) { return i * (i + 1) / 2 + j; }

// ---------------------------------------------------------------------------
// Pass 1: per-(batch,group) block. Each thread owns whole 16-channel float4
// column-groups: 16 coalesced float4 loads -> 544 FMA into a private 136-cell
// triangle. No shuffles in the hot loop. Endgame: 6-stage xor reduce + one
// atomicAdd per cell per wave.
// Register budget: accT 136 + v 64 + s 16 + addr ~ 230 < 256 (launch_bounds 256,2).
// ---------------------------------------------------------------------------
__global__ __launch_bounds__(256, 2) void whiten_stats(const float* __restrict__ x,
                                                       float* __restrict__ sums,
                                                       float* __restrict__ gram) {
    const int b = blockIdx.x, g = blockIdx.y;
    const float* base = x + ((size_t)b * D_FEAT + (size_t)g * GS) * HW;

    float accT[TRI];
    float s[GS];
#pragma unroll
    for (int t = 0; t < TRI; ++t) accT[t] = 0.f;
#pragma unroll
    for (int j = 0; j < GS; ++j) s[j] = 0.f;

    for (int p4 = threadIdx.x; p4 < P4; p4 += 256) {
        float4 v[GS];
#pragma unroll
        for (int j = 0; j < GS; ++j)
            v[j] = ((const float4*)(base + (size_t)j * HW))[p4];
#pragma unroll
        for (int i = 0; i < GS; ++i) {
            s[i] += (v[i].x + v[i].y) + (v[i].z + v[i].w);
#pragma unroll
            for (int j = 0; j <= i; ++j) {
                float a = accT[tidx(i, j)];
                a = fmaf(v[i].x, v[j].x, a);
                a = fmaf(v[i].y, v[j].y, a);
                a = fmaf(v[i].z, v[j].z, a);
                a = fmaf(v[i].w, v[j].w, a);
                accT[tidx(i, j)] = a;
            }
        }
    }

    // reduce the 152 per-lane partials across the 64-lane wave
#pragma unroll
    for (int m = 1; m <= 32; m <<= 1) {
#pragma unroll
        for (int j = 0; j < GS; ++j) s[j] += __shfl_xor(s[j], m, 64);
#pragma unroll
        for (int t = 0; t < TRI; ++t) accT[t] += __shfl_xor(accT[t], m, 64);
    }

    if ((threadIdx.x & 63) == 0) {
#pragma unroll
        for (int j = 0; j < GS; ++j) atomicAdd(&sums[g * GS + j], s[j]);
#pragma unroll
        for (int t = 0; t < TRI; ++t) atomicAdd(&gram[g * TRI + t], accT[t]);
    }
}

// ---------------------------------------------------------------------------
// Pass 2: sigma -> Cholesky -> W = inv(T) (packed tri) + bias = -W mu.
// 16 groups in 16 lanes of one wave; no launch_bounds (regs unconstrained).
// ---------------------------------------------------------------------------
__global__ void whiten_solve(const float* __restrict__ sums,
                             const float* __restrict__ gram,
                             float* __restrict__ wtri,
                             float* __restrict__ bias) {
    const int g = threadIdx.x;
    if (g >= NGROUPS) return;

    float mu[GS];
#pragma unroll
    for (int j = 0; j < GS; ++j) mu[j] = sums[g * GS + j] * (1.0f / (float)NTOT);

    float S[TRI];
#pragma unroll
    for (int i = 0; i < GS; ++i) {
#pragma unroll
        for (int j = 0; j <= i; ++j) {
            float sg = (gram[g * TRI + tidx(i, j)] - (float)NTOT * mu[i] * mu[j])
                       * (1.0f / (float)(NTOT - 1));
            sg *= (1.0f - EPS_W);
            if (i == j) sg += EPS_W;
            S[tidx(i, j)] = sg;
        }
    }

    // In-place Cholesky: S becomes T (lower).
#pragma unroll
    for (int cc = 0; cc < GS; ++cc) {
        float d = S[tidx(cc, cc)];
#pragma unroll
        for (int k = 0; k < cc; ++k) d -= S[tidx(cc, k)] * S[tidx(cc, k)];
        d = sqrtf(d);
        S[tidx(cc, cc)] = d;
        const float inv = 1.0f / d;
#pragma unroll
        for (int i = cc + 1; i < GS; ++i) {
            float t = S[tidx(i, cc)];
#pragma unroll
            for (int k = 0; k < cc; ++k) t -= S[tidx(i, k)] * S[tidx(cc, k)];
            S[tidx(i, cc)] = t * inv;
        }
    }

    // In-place inverse of lower-triangular T: S becomes W = T^{-1}.
#pragma unroll
    for (int cc = 0; cc < GS; ++cc) {
        const float wcc = 1.0f / S[tidx(cc, cc)];
        S[tidx(cc, cc)] = wcc;
#pragma unroll
        for (int i = cc + 1; i < GS; ++i) {
            float a = 0.0f;
#pragma unroll
            for (int k = cc; k < i; ++k) a += S[tidx(i, k)] * S[tidx(k, cc)];
            S[tidx(i, cc)] = -a / S[tidx(i, i)];
        }
    }

#pragma unroll
    for (int t = 0; t < TRI; ++t) wtri[g * TRI + t] = S[t];
#pragma unroll
    for (int i = 0; i < GS; ++i) {
        float acc = 0.f;
#pragma unroll
        for (int j = 0; j <= i; ++j) acc += S[tidx(i, j)] * mu[j];
        bias[g * GS + i] = -acc;
    }
}

// ---------------------------------------------------------------------------
// Pass 3: out = W x + bias. Same decomposition as pass 1: thread owns full
// 16-channel float4 column-groups; W triangle + bias wave-uniform in regs.
// ---------------------------------------------------------------------------
__global__ __launch_bounds__(256, 2) void whiten_apply(const float* __restrict__ x,
                                                       const float* __restrict__ wtri,
                                                       const float* __restrict__ bias,
                                                       float* __restrict__ out) {
    const int b = blockIdx.x, g = blockIdx.y;
    const size_t off0 = ((size_t)b * D_FEAT + (size_t)g * GS) * HW;
    const float* base = x + off0;
    float* obase = out + off0;

    float w[TRI], bb[GS];
#pragma unroll
    for (int t = 0; t < TRI; ++t) w[t] = wtri[g * TRI + t];
#pragma unroll
    for (int j = 0; j < GS; ++j) bb[j] = bias[g * GS + j];

    for (int p4 = threadIdx.x; p4 < P4; p4 += 256) {
        float4 v[GS];
#pragma unroll
        for (int j = 0; j < GS; ++j)
            v[j] = ((const float4*)(base + (size_t)j * HW))[p4];
#pragma unroll
        for (int i = 0; i < GS; ++i) {
            float4 o;
            o.x = bb[i]; o.y = bb[i]; o.z = bb[i]; o.w = bb[i];
#pragma unroll
            for (int j = 0; j <= i; ++j) {
                const float wij = w[tidx(i, j)];
                o.x = fmaf(wij, v[j].x, o.x);
                o.y = fmaf(wij, v[j].y, o.y);
                o.z = fmaf(wij, v[j].z, o.z);
                o.w = fmaf(wij, v[j].w, o.w);
            }
            ((float4*)(obase + (size_t)i * HW))[p4] = o;
        }
    }
}

extern "C" void kernel_launch(void* const* d_in, const int* in_sizes, int n_in,
                              void* d_out, int out_size, void* d_ws, size_t ws_size,
                              hipStream_t stream) {
    const float* x = (const float*)d_in[0];
    float* out = (float*)d_out;

    float* ws   = (float*)d_ws;
    float* sums = ws;          // 256
    float* gram = ws + 256;    // 2176
    float* wtri = ws + 2432;   // 2176
    float* bias = ws + 4608;   // 256

    hipMemsetAsync(ws, 0, 2432 * sizeof(float), stream);

    whiten_stats<<<dim3(M_BATCH, NGROUPS), 256, 0, stream>>>(x, sums, gram);
    whiten_solve<<<1, 64, 0, stream>>>(sums, gram, wtri, bias);
    whiten_apply<<<dim3(M_BATCH, NGROUPS), 256, 0, stream>>>(x, wtri, bias, out);
}

// Round 4
// 393.927 us; speedup vs baseline: 1.0194x; 1.0194x over previous
//
#include <hip/hip_runtime.h>

// x = (32, 256, 56, 56) fp32; 16 groups of 16 channels
#define M_BATCH 32
#define D_FEAT 256
#define HW 3136
#define NGROUPS 16
#define GS 16
#define NTOT (M_BATCH * HW)
#define TRI 136
#define EPS_W 1e-6f
#define P4 (HW / 4)  // 784 float4 column-groups per channel row

__device__ __host__ constexpr int tidx(int i, int j) { return i * (i + 1) / 2 + j; }

// ---------------------------------------------------------------------------
// Pass 1: per-(batch,group) block. Each thread owns whole 16-channel float4
// column-groups: 16 coalesced float4 loads -> 544 FMA into a private 136-cell
// triangle. No shuffles in the hot loop.
//
// Register note (R2/R3 post-mortem): the backend allocates for 2x the
// launch_bounds min-waves arg -> (256,2) gave a 128-VGPR cap and a 120 MB
// scratch spill. amdgpu_waves_per_eu(1,1) pins the allocator at 1 wave/EU
// (512 VGPRs available); ~240 live here. 4 waves/CU x 16 outstanding float4
// loads = 64 KB in flight/CU >> the ~9 KB needed to cover HBM latency.
// ---------------------------------------------------------------------------
__global__
__attribute__((amdgpu_flat_work_group_size(256, 256), amdgpu_waves_per_eu(1, 1)))
void whiten_stats(const float* __restrict__ x,
                  float* __restrict__ sums,
                  float* __restrict__ gram) {
    const int b = blockIdx.x, g = blockIdx.y;
    const float* base = x + ((size_t)b * D_FEAT + (size_t)g * GS) * HW;

    float accT[TRI];
    float s[GS];
#pragma unroll
    for (int t = 0; t < TRI; ++t) accT[t] = 0.f;
#pragma unroll
    for (int j = 0; j < GS; ++j) s[j] = 0.f;

    for (int p4 = threadIdx.x; p4 < P4; p4 += 256) {
        float4 v[GS];
#pragma unroll
        for (int j = 0; j < GS; ++j)
            v[j] = ((const float4*)(base + (size_t)j * HW))[p4];
#pragma unroll
        for (int i = 0; i < GS; ++i) {
            s[i] += (v[i].x + v[i].y) + (v[i].z + v[i].w);
#pragma unroll
            for (int j = 0; j <= i; ++j) {
                float a = accT[tidx(i, j)];
                a = fmaf(v[i].x, v[j].x, a);
                a = fmaf(v[i].y, v[j].y, a);
                a = fmaf(v[i].z, v[j].z, a);
                a = fmaf(v[i].w, v[j].w, a);
                accT[tidx(i, j)] = a;
            }
        }
    }

    // reduce the 152 per-lane partials across the 64-lane wave
#pragma unroll
    for (int m = 1; m <= 32; m <<= 1) {
#pragma unroll
        for (int j = 0; j < GS; ++j) s[j] += __shfl_xor(s[j], m, 64);
#pragma unroll
        for (int t = 0; t < TRI; ++t) accT[t] += __shfl_xor(accT[t], m, 64);
    }

    if ((threadIdx.x & 63) == 0) {
#pragma unroll
        for (int j = 0; j < GS; ++j) atomicAdd(&sums[g * GS + j], s[j]);
#pragma unroll
        for (int t = 0; t < TRI; ++t) atomicAdd(&gram[g * TRI + t], accT[t]);
    }
}

// ---------------------------------------------------------------------------
// Pass 2: sigma -> Cholesky -> W = inv(T) (packed tri) + bias = -W mu.
// 16 groups in 16 lanes of one wave.
// ---------------------------------------------------------------------------
__global__ void whiten_solve(const float* __restrict__ sums,
                             const float* __restrict__ gram,
                             float* __restrict__ wtri,
                             float* __restrict__ bias) {
    const int g = threadIdx.x;
    if (g >= NGROUPS) return;

    float mu[GS];
#pragma unroll
    for (int j = 0; j < GS; ++j) mu[j] = sums[g * GS + j] * (1.0f / (float)NTOT);

    float S[TRI];
#pragma unroll
    for (int i = 0; i < GS; ++i) {
#pragma unroll
        for (int j = 0; j <= i; ++j) {
            float sg = (gram[g * TRI + tidx(i, j)] - (float)NTOT * mu[i] * mu[j])
                       * (1.0f / (float)(NTOT - 1));
            sg *= (1.0f - EPS_W);
            if (i == j) sg += EPS_W;
            S[tidx(i, j)] = sg;
        }
    }

    // In-place Cholesky: S becomes T (lower).
#pragma unroll
    for (int cc = 0; cc < GS; ++cc) {
        float d = S[tidx(cc, cc)];
#pragma unroll
        for (int k = 0; k < cc; ++k) d -= S[tidx(cc, k)] * S[tidx(cc, k)];
        d = sqrtf(d);
        S[tidx(cc, cc)] = d;
        const float inv = 1.0f / d;
#pragma unroll
        for (int i = cc + 1; i < GS; ++i) {
            float t = S[tidx(i, cc)];
#pragma unroll
            for (int k = 0; k < cc; ++k) t -= S[tidx(i, k)] * S[tidx(cc, k)];
            S[tidx(i, cc)] = t * inv;
        }
    }

    // In-place inverse of lower-triangular T: S becomes W = T^{-1}.
#pragma unroll
    for (int cc = 0; cc < GS; ++cc) {
        const float wcc = 1.0f / S[tidx(cc, cc)];
        S[tidx(cc, cc)] = wcc;
#pragma unroll
        for (int i = cc + 1; i < GS; ++i) {
            float a = 0.0f;
#pragma unroll
            for (int k = cc; k < i; ++k) a += S[tidx(i, k)] * S[tidx(k, cc)];
            S[tidx(i, cc)] = -a / S[tidx(i, i)];
        }
    }

#pragma unroll
    for (int t = 0; t < TRI; ++t) wtri[g * TRI + t] = S[t];
#pragma unroll
    for (int i = 0; i < GS; ++i) {
        float acc = 0.f;
#pragma unroll
        for (int j = 0; j <= i; ++j) acc += S[tidx(i, j)] * mu[j];
        bias[g * GS + i] = -acc;
    }
}

// ---------------------------------------------------------------------------
// Pass 3: out = W x + bias. Thread owns full 16-channel float4 column-groups;
// W triangle + bias wave-uniform in regs. Same register-pinning as pass 1
// (~230 live: w 136 + v 64 + bb 16).
// ---------------------------------------------------------------------------
__global__
__attribute__((amdgpu_flat_work_group_size(256, 256), amdgpu_waves_per_eu(1, 1)))
void whiten_apply(const float* __restrict__ x,
                  const float* __restrict__ wtri,
                  const float* __restrict__ bias,
                  float* __restrict__ out) {
    const int b = blockIdx.x, g = blockIdx.y;
    const size_t off0 = ((size_t)b * D_FEAT + (size_t)g * GS) * HW;
    const float* base = x + off0;
    float* obase = out + off0;

    float w[TRI], bb[GS];
#pragma unroll
    for (int t = 0; t < TRI; ++t) w[t] = wtri[g * TRI + t];
#pragma unroll
    for (int j = 0; j < GS; ++j) bb[j] = bias[g * GS + j];

    for (int p4 = threadIdx.x; p4 < P4; p4 += 256) {
        float4 v[GS];
#pragma unroll
        for (int j = 0; j < GS; ++j)
            v[j] = ((const float4*)(base + (size_t)j * HW))[p4];
#pragma unroll
        for (int i = 0; i < GS; ++i) {
            float4 o;
            o.x = bb[i]; o.y = bb[i]; o.z = bb[i]; o.w = bb[i];
#pragma unroll
            for (int j = 0; j <= i; ++j) {
                const float wij = w[tidx(i, j)];
                o.x = fmaf(wij, v[j].x, o.x);
                o.y = fmaf(wij, v[j].y, o.y);
                o.z = fmaf(wij, v[j].z, o.z);
                o.w = fmaf(wij, v[j].w, o.w);
            }
            ((float4*)(obase + (size_t)i * HW))[p4] = o;
        }
    }
}

extern "C" void kernel_launch(void* const* d_in, const int* in_sizes, int n_in,
                              void* d_out, int out_size, void* d_ws, size_t ws_size,
                              hipStream_t stream) {
    const float* x = (const float*)d_in[0];
    float* out = (float*)d_out;

    float* ws   = (float*)d_ws;
    float* sums = ws;          // 256
    float* gram = ws + 256;    // 2176
    float* wtri = ws + 2432;   // 2176
    float* bias = ws + 4608;   // 256

    hipMemsetAsync(ws, 0, 2432 * sizeof(float), stream);

    whiten_stats<<<dim3(M_BATCH, NGROUPS), 256, 0, stream>>>(x, sums, gram);
    whiten_solve<<<1, 64, 0, stream>>>(sums, gram, wtri, bias);
    whiten_apply<<<dim3(M_BATCH, NGROUPS), 256, 0, stream>>>(x, wtri, bias, out);
}